// Round 7
// baseline (396.250 us; speedup 1.0000x reference)
//
#include <hip/hip_runtime.h>
#include <hip/hip_bf16.h>
#include <hip/hip_cooperative_groups.h>

namespace cg = cooperative_groups;

typedef __bf16 bf16_t;
typedef __bf16 bf16x4v __attribute__((ext_vector_type(4)));
typedef __bf16 bf16x8 __attribute__((ext_vector_type(8)));
typedef float  f32x4  __attribute__((ext_vector_type(4)));

// address-space pointer types for global_load_lds
typedef __attribute__((address_space(1))) void* gptr_t;
typedef __attribute__((address_space(3))) void* lptr_t;

#define B_BATCH  4
#define T_SEQ    2048
#define D_MODEL  1024
#define N_HEADS  16
#define HEAD_DIM 64
#define M_ROWS   (B_BATCH * T_SEQ)   // 8192

#define PROW 40    // attn Ps row elems (80B: 16B-aligned reads, odd-stride banks)

// exp(x/8) = exp2(x * 0.125 * log2(e)); folded into Q at the qkv epilogue
#define EXP2_SCALE 0.1803368801111204f

// ---------------------------------------------------------------------------
// prep_k: fused weight transpose+cast (blocks 0..4095) and x fp32->bf16
// convert (blocks 4096..6143). Independent work, one dispatch instead of two
// (saves a kernel boundary drain). Barrier use is block-uniform.
// ---------------------------------------------------------------------------
__global__ __launch_bounds__(256) void prep_k(
    const float* __restrict__ x, const float* __restrict__ w0,
    const float* __restrict__ w1, const float* __restrict__ w2,
    const float* __restrict__ w3,
    bf16_t* __restrict__ xb, bf16_t* __restrict__ wT)
{
    __shared__ bf16_t tile[32][33];
    const int bid = blockIdx.x;
    if (bid < 4096) {
        const int z = bid >> 10, rem = bid & 1023;
        const int n0 = (rem & 31) * 32, k0 = (rem >> 5) * 32;
        const float* w = (z == 0) ? w0 : (z == 1) ? w1 : (z == 2) ? w2 : w3;
        bf16_t* o = wT + (size_t)z * D_MODEL * D_MODEL;
        const int tx = threadIdx.x & 31, ty = threadIdx.x >> 5;   // 32 x 8
        for (int i = 0; i < 4; i++)
            tile[ty + i * 8][tx] =
                (bf16_t)w[(size_t)(k0 + ty + i * 8) * D_MODEL + n0 + tx];
        __syncthreads();
        for (int i = 0; i < 4; i++)
            o[(size_t)(n0 + ty + i * 8) * D_MODEL + k0 + tx] = tile[tx][ty + i * 8];
    } else {
        const size_t tid = (size_t)(bid - 4096) * 256 + threadIdx.x;
        for (int rep = 0; rep < 4; rep++) {
            const size_t i = (tid + (size_t)rep * 524288) * 4;
            const f32x4 v = *(const f32x4*)&x[i];
            bf16x4v o;
            for (int e = 0; e < 4; e++) o[e] = (bf16_t)v[e];
            *(bf16x4v*)&xb[i] = o;
        }
    }
}

// ---------------------------------------------------------------------------
// Fused QKV GEMM, 256x128 tile, 8 waves (4M x 2N), BK=64, K-tile dbuf.
// 768 blocks = exactly 3.0 rounds @ 1 block/CU. One barrier per K-tile;
// ALL of tile t+1's global_load_lds issues go immediately after the top
// barrier (round-7: was spread across s-phases; now a full tile of cover
// for every load). Chunk-XOR swizzle both sides. z==0 (Q) epilogue
// pre-scales by EXP2_SCALE.
// ---------------------------------------------------------------------------
__global__ __launch_bounds__(512, 2) void qkv_k(
    const bf16_t* __restrict__ A, const bf16_t* __restrict__ BT,
    const float* __restrict__ bq, const float* __restrict__ bk,
    const float* __restrict__ bv,
    bf16_t* __restrict__ qk_out, bf16_t* __restrict__ vt_out)
{
    __shared__ __attribute__((aligned(16))) bf16_t smem[49152];   // 96 KB
    // elems: As[p] at p*16384; Bs[p] at 32768 + p*8192

    const int tid = threadIdx.x;
    const int f0 = blockIdx.y * 24 + blockIdx.x;        // 0..767
    const int f  = (f0 & 7) * 96 + (f0 >> 3);           // bijective XCD swizzle
    const int n_t = f % 24, m_t = f / 24;
    const int m0 = m_t * 256, n0 = n_t * 128;
    const int z  = n0 >> 10;                            // 0=q 1=k 2=v
    const int w = tid >> 6, lane = tid & 63, quad = lane >> 4, l16 = lane & 15;
    const int wm = w >> 1, wn = w & 1;                  // 4M x 2N wave grid
    const int srow = lane >> 3;                         // staging row in 8-group
    const int scol = ((lane & 7) ^ srow) * 8;           // source pre-swizzle
    const int rx = l16 & 7;                             // read-side XOR

    f32x4 acc[4][4] = {};

    // prologue: stage tile 0 into buffer 0 (4 A + 2 B issues per wave)
    for (int it = 0; it < 4; it++) {
        const int R = w * 32 + it * 8;
        __builtin_amdgcn_global_load_lds(
            (gptr_t)&A[(size_t)(m0 + R + srow) * D_MODEL + scol],
            (lptr_t)&smem[R * 64], 16, 0, 0);
    }
    for (int it = 0; it < 2; it++) {
        const int R = w * 16 + it * 8;
        __builtin_amdgcn_global_load_lds(
            (gptr_t)&BT[(size_t)(n0 + R + srow) * D_MODEL + scol],
            (lptr_t)&smem[32768 + R * 64], 16, 0, 0);
    }

    for (int t = 0; t < 16; t++) {
        __syncthreads();   // tile t resident; buf[t^1] free to overwrite
        const bf16_t* Ac = &smem[(t & 1) * 16384];
        const bf16_t* Bc = &smem[32768 + (t & 1) * 8192];
        bf16_t* An = &smem[((t + 1) & 1) * 16384];
        bf16_t* Bn = &smem[32768 + ((t + 1) & 1) * 8192];
        const int kb = (t + 1) * 64;

        // issue ALL of tile t+1's stages now: full tile of latency cover
        if (t + 1 < 16) {
            #pragma unroll
            for (int it = 0; it < 4; it++) {
                const int R = w * 32 + it * 8;
                __builtin_amdgcn_global_load_lds(
                    (gptr_t)&A[(size_t)(m0 + R + srow) * D_MODEL + kb + scol],
                    (lptr_t)&An[R * 64], 16, 0, 0);
            }
            #pragma unroll
            for (int it = 0; it < 2; it++) {
                const int R = w * 16 + it * 8;
                __builtin_amdgcn_global_load_lds(
                    (gptr_t)&BT[(size_t)(n0 + R + srow) * D_MODEL + kb + scol],
                    (lptr_t)&Bn[R * 64], 16, 0, 0);
            }
        }

        #pragma unroll
        for (int s = 0; s < 2; s++) {
            const int rc = ((quad + s * 4) ^ rx) * 8;
            bf16x8 bfr[4];
            #pragma unroll
            for (int j = 0; j < 4; j++)
                bfr[j] = *(const bf16x8*)&Bc[(wn * 64 + j * 16 + l16) * 64 + rc];
            bf16x8 af[4];
            #pragma unroll
            for (int i = 0; i < 4; i++)
                af[i] = *(const bf16x8*)&Ac[(wm * 64 + i * 16 + l16) * 64 + rc];
            __builtin_amdgcn_s_setprio(1);
            #pragma unroll
            for (int i = 0; i < 4; i++)
                #pragma unroll
                for (int j = 0; j < 4; j++)
                    acc[i][j] = __builtin_amdgcn_mfma_f32_16x16x32_bf16(
                        af[i], bfr[j], acc[i][j], 0, 0, 0);
            __builtin_amdgcn_s_setprio(0);
        }
    }

    __syncthreads();   // all LDS reads done; alias smem as C-stage

    const float* bias = (z == 0) ? bq : (z == 1) ? bk : bv;
    const float qscale = (z == 0) ? EXP2_SCALE : 1.0f;
    const int ncol0 = n0 & 1023;
    float bj[4];
    for (int j = 0; j < 4; j++)
        bj[j] = bias[ncol0 + wn * 64 + j * 16 + l16];

    const int bidx = m0 >> 11, t0 = m0 & 2047, hbase = ncol0 >> 6;
    if (z < 2) {
        bf16_t (*Cs)[136] = reinterpret_cast<bf16_t(*)[136]>(smem);   // 34816 el
        for (int ai = 0; ai < 4; ai++)
            for (int r = 0; r < 4; r++) {
                const int row = wm * 64 + ai * 16 + quad * 4 + r;
                for (int j = 0; j < 4; j++)
                    Cs[row][wn * 64 + j * 16 + l16] =
                        (bf16_t)((acc[ai][j][r] + bj[j]) * qscale);
            }
        __syncthreads();
        bf16_t* outp = qk_out + (size_t)z * ((size_t)M_ROWS * D_MODEL);
        for (int p = 0; p < 8; p++) {
            const int chunk = p * 512 + tid;
            const int sub = chunk & 15, tt = chunk >> 4;
            const int hl = sub >> 3, sub8 = sub & 7;
            const bf16x8 val = *(const bf16x8*)&Cs[tt][hl * 64 + sub8 * 8];
            *(bf16x8*)&outp[(((size_t)(bidx * N_HEADS + hbase + hl)) * T_SEQ + t0 + tt)
                            * HEAD_DIM + sub8 * 8] = val;
        }
    } else {
        bf16_t (*CsV)[264] = reinterpret_cast<bf16_t(*)[264]>(smem);  // 33792 el
        for (int ai = 0; ai < 4; ai++)
            for (int r = 0; r < 4; r++) {
                const int row = wm * 64 + ai * 16 + quad * 4 + r;
                for (int j = 0; j < 4; j++)
                    CsV[wn * 64 + j * 16 + l16][row] = (bf16_t)(acc[ai][j][r] + bj[j]);
            }
        __syncthreads();
        for (int p = 0; p < 8; p++) {
            const int chunk = p * 512 + tid;
            const int sub = chunk & 31, r = chunk >> 5;
            const int h = hbase + (r >> 6), hd = r & 63;
            const bf16x8 val = *(const bf16x8*)&CsV[r][sub * 8];
            *(bf16x8*)&vt_out[(((size_t)(bidx * N_HEADS + h)) * HEAD_DIM + hd) * T_SEQ
                              + t0 + sub * 8] = val;
        }
    }
}

// ---------------------------------------------------------------------------
// Fused Proj + LayerNorm, COOPERATIVE (round-7): 256 blocks x 512 threads,
// 96 KB LDS -> exactly 1 block/CU -> guaranteed co-resident. Phase 1 is the
// 256x128 pipelined proj GEMM (fp32 stores to proj buffer). Then
// __threadfence() (device-scope, cross-XCD visibility) + grid.sync().
// Phase 2: each block LayerNorms 32 rows (8 waves x 4 rows, wave-per-row,
// no LDS, no block barrier). Removes the ln dispatch + one boundary drain.
// ---------------------------------------------------------------------------
__global__ __launch_bounds__(512, 1) void projln_k(
    const bf16_t* __restrict__ A, const bf16_t* __restrict__ BT,
    const float* __restrict__ bias, float* __restrict__ proj,
    const float* __restrict__ gamma, const float* __restrict__ beta,
    float* __restrict__ out)
{
    __shared__ __attribute__((aligned(16))) bf16_t smem[49152];   // 96 KB

    const int tid = threadIdx.x;
    const int f0 = blockIdx.x;                          // 0..255
    const int f  = (f0 & 7) * 32 + (f0 >> 3);           // bijective XCD swizzle
    const int n_t = f & 7, m_t = f >> 3;
    const int m0 = m_t * 256, n0 = n_t * 128;
    const int w = tid >> 6, lane = tid & 63, quad = lane >> 4, l16 = lane & 15;
    const int wm = w >> 1, wn = w & 1;
    const int srow = lane >> 3;
    const int scol = ((lane & 7) ^ srow) * 8;
    const int rx = l16 & 7;

    f32x4 acc[4][4] = {};

    for (int it = 0; it < 4; it++) {
        const int R = w * 32 + it * 8;
        __builtin_amdgcn_global_load_lds(
            (gptr_t)&A[(size_t)(m0 + R + srow) * D_MODEL + scol],
            (lptr_t)&smem[R * 64], 16, 0, 0);
    }
    for (int it = 0; it < 2; it++) {
        const int R = w * 16 + it * 8;
        __builtin_amdgcn_global_load_lds(
            (gptr_t)&BT[(size_t)(n0 + R + srow) * D_MODEL + scol],
            (lptr_t)&smem[32768 + R * 64], 16, 0, 0);
    }

    for (int t = 0; t < 16; t++) {
        __syncthreads();
        const bf16_t* Ac = &smem[(t & 1) * 16384];
        const bf16_t* Bc = &smem[32768 + (t & 1) * 8192];
        bf16_t* An = &smem[((t + 1) & 1) * 16384];
        bf16_t* Bn = &smem[32768 + ((t + 1) & 1) * 8192];
        const int kb = (t + 1) * 64;

        if (t + 1 < 16) {
            #pragma unroll
            for (int it = 0; it < 4; it++) {
                const int R = w * 32 + it * 8;
                __builtin_amdgcn_global_load_lds(
                    (gptr_t)&A[(size_t)(m0 + R + srow) * D_MODEL + kb + scol],
                    (lptr_t)&An[R * 64], 16, 0, 0);
            }
            #pragma unroll
            for (int it = 0; it < 2; it++) {
                const int R = w * 16 + it * 8;
                __builtin_amdgcn_global_load_lds(
                    (gptr_t)&BT[(size_t)(n0 + R + srow) * D_MODEL + kb + scol],
                    (lptr_t)&Bn[R * 64], 16, 0, 0);
            }
        }

        #pragma unroll
        for (int s = 0; s < 2; s++) {
            const int rc = ((quad + s * 4) ^ rx) * 8;
            bf16x8 bfr[4];
            #pragma unroll
            for (int j = 0; j < 4; j++)
                bfr[j] = *(const bf16x8*)&Bc[(wn * 64 + j * 16 + l16) * 64 + rc];
            bf16x8 af[4];
            #pragma unroll
            for (int i = 0; i < 4; i++)
                af[i] = *(const bf16x8*)&Ac[(wm * 64 + i * 16 + l16) * 64 + rc];
            __builtin_amdgcn_s_setprio(1);
            #pragma unroll
            for (int i = 0; i < 4; i++)
                #pragma unroll
                for (int j = 0; j < 4; j++)
                    acc[i][j] = __builtin_amdgcn_mfma_f32_16x16x32_bf16(
                        af[i], bfr[j], acc[i][j], 0, 0, 0);
            __builtin_amdgcn_s_setprio(0);
        }
    }

    float bj[4];
    for (int j = 0; j < 4; j++)
        bj[j] = bias[n0 + wn * 64 + j * 16 + l16];

    for (int i = 0; i < 4; i++)
        for (int r = 0; r < 4; r++) {
            const int rg = m0 + wm * 64 + i * 16 + quad * 4 + r;
            for (int j = 0; j < 4; j++) {
                const int cg = n0 + wn * 64 + j * 16 + l16;
                proj[(size_t)rg * D_MODEL + cg] = acc[i][j][r] + bj[j];
            }
        }

    // ---- grid-wide handoff: proj fully written -> LayerNorm phase ----
    __threadfence();
    cg::this_grid().sync();

    // phase 2: LayerNorm. Block f0 owns rows [f0*32, f0*32+32); wave w does
    // rows f0*32 + w*4 .. +3 (wave-per-row, 16 elems/lane as 4 x f32x4).
    const int row0 = f0 * 32 + w * 4;
    for (int rr = 0; rr < 4; rr++) {
        const int row = row0 + rr;
        const float* p = proj + (size_t)row * D_MODEL;
        f32x4 v[4];
        float s1 = 0.f, s2 = 0.f;
        for (int e = 0; e < 4; e++) {
            v[e] = *(const f32x4*)&p[e * 256 + lane * 4];
            for (int k = 0; k < 4; k++) { s1 += v[e][k]; s2 += v[e][k] * v[e][k]; }
        }
        for (int off = 32; off >= 1; off >>= 1) {
            s1 += __shfl_xor(s1, off, 64);
            s2 += __shfl_xor(s2, off, 64);
        }
        const float mu  = s1 * (1.f / D_MODEL);
        const float var = s2 * (1.f / D_MODEL) - mu * mu;
        const float rstd = rsqrtf(var + 1e-5f);
        float* o = out + (size_t)row * D_MODEL;
        for (int e = 0; e < 4; e++) {
            const int c = e * 256 + lane * 4;
            const f32x4 g4 = *(const f32x4*)&gamma[c];
            const f32x4 b4 = *(const f32x4*)&beta[c];
            f32x4 ov;
            for (int k = 0; k < 4; k++) ov[k] = (v[e][k] - mu) * rstd * g4[k] + b4[k];
            *(f32x4*)&o[c] = ov;
        }
    }
}

// ---------------------------------------------------------------------------
// Flash attention (unchanged round-6 structure — the 87 us control).
// ---------------------------------------------------------------------------
__global__ __launch_bounds__(256, 4) void attn_k(
    const bf16_t* __restrict__ Q, const bf16_t* __restrict__ K,
    const bf16_t* __restrict__ VT, bf16_t* __restrict__ O)
{
    __shared__ __attribute__((aligned(16))) bf16_t Ks[2][64 * 64];   // 16 KB
    __shared__ __attribute__((aligned(16))) bf16_t Vs[64 * 64];      //  8 KB
    __shared__ __attribute__((aligned(16))) bf16_t Ps[4][32][PROW];  // 10 KB

    const int tid = threadIdx.x;
    const int f = blockIdx.y * 16 + blockIdx.x;
    const int xcd = f & 7, j = f >> 3;
    const int bh = xcd * 8 + (j & 7);
    const int qbase = (j >> 3) * 128;
    const int b = bh >> 4, h = bh & 15;
    const int w = tid >> 6, lane = tid & 63, quad = lane >> 4, l16 = lane & 15;
    const size_t head_off = (size_t)bh * T_SEQ * HEAD_DIM;
    const bf16_t* Qh  = Q  + head_off;
    const bf16_t* Kh  = K  + head_off;
    const bf16_t* VTh = VT + head_off;

    const int srow = lane >> 3;
    const int scol = ((lane & 7) ^ srow) * 8;

    const int rxor = l16 & 7;
    const int rc0 = ((0 + quad) ^ rxor) * 8;
    const int rc1 = ((4 + quad) ^ rxor) * 8;

    bf16x8 bq[2][2];
    for (int iq = 0; iq < 2; iq++)
        for (int s = 0; s < 2; s++)
            bq[iq][s] = *(const bf16x8*)
                &Qh[(size_t)(qbase + w * 32 + iq * 16 + l16) * HEAD_DIM + s * 32 + quad * 8];

    bf16x8 vone;
    for (int e = 0; e < 8; e++) vone[e] = (bf16_t)1.0f;

    for (int it = 0; it < 2; it++) {
        const int R = w * 16 + it * 8;
        __builtin_amdgcn_global_load_lds(
            (gptr_t)&Kh[(size_t)(R + srow) * HEAD_DIM + scol],
            (lptr_t)&Ks[0][R * 64], 16, 0, 0);
    }

    f32x4 Oacc[2][4] = {};
    f32x4 lacc[2] = {};

    for (int kt = 0; kt < T_SEQ / 64; kt++) {
        const int kbase = kt * 64;
        __syncthreads();   // (A) PV(kt-1) reads done; K(kt) resident
        const bf16_t* Kc = Ks[kt & 1];

        for (int it = 0; it < 2; it++) {
            const int R = w * 16 + it * 8;
            __builtin_amdgcn_global_load_lds(
                (gptr_t)&VTh[(size_t)(R + srow) * T_SEQ + kbase + scol],
                (lptr_t)&Vs[R * 64], 16, 0, 0);
        }
        if (kt + 1 < T_SEQ / 64) {
            bf16_t* Kn = Ks[(kt + 1) & 1];
            for (int it = 0; it < 2; it++) {
                const int R = w * 16 + it * 8;
                __builtin_amdgcn_global_load_lds(
                    (gptr_t)&Kh[(size_t)(kbase + 64 + R + srow) * HEAD_DIM + scol],
                    (lptr_t)&Kn[R * 64], 16, 0, 0);
            }
        }

        f32x4 St[4][2] = {};
        for (int s = 0; s < 2; s++) {
            const int rc = s ? rc1 : rc0;
            bf16x8 ak[4];
            for (int jk = 0; jk < 4; jk++)
                ak[jk] = *(const bf16x8*)&Kc[(jk * 16 + l16) * 64 + rc];
            __builtin_amdgcn_s_setprio(1);
            for (int jk = 0; jk < 4; jk++)
                for (int iq = 0; iq < 2; iq++)
                    St[jk][iq] = __builtin_amdgcn_mfma_f32_16x16x32_bf16(
                        ak[jk], bq[iq][s], St[jk][iq], 0, 0, 0);
            __builtin_amdgcn_s_setprio(0);
        }

        // half 0: keys kbase..kbase+31 (Q pre-scaled -> exp2 direct)
        for (int kk = 0; kk < 2; kk++)
            for (int iq = 0; iq < 2; iq++) {
                bf16x4v pv;
                for (int r = 0; r < 4; r++)
                    pv[r] = (bf16_t)__builtin_amdgcn_exp2f(St[kk][iq][r]);
                *(bf16x4v*)&Ps[w][iq * 16 + l16][kk * 16 + quad * 4] = pv;
            }
        asm volatile("" ::: "memory");

        __syncthreads();   // (B) V(kt) + K(kt+1) landed

        {   // PV half 0 (+ ones-MFMA row-sum)
            bf16x8 ap[2], bv4[4];
            for (int iq = 0; iq < 2; iq++)
                ap[iq] = *(const bf16x8*)&Ps[w][iq * 16 + l16][quad * 8];
            for (int jn = 0; jn < 4; jn++)
                bv4[jn] = *(const bf16x8*)&Vs[(jn * 16 + l16) * 64 + rc0];
            __builtin_amdgcn_s_setprio(1);
            for (int iq = 0; iq < 2; iq++) {
                for (int jn = 0; jn < 4; jn++)
                    Oacc[iq][jn] = __builtin_amdgcn_mfma_f32_16x16x32_bf16(
                        ap[iq], bv4[jn], Oacc[iq][jn], 0, 0, 0);
                lacc[iq] = __builtin_amdgcn_mfma_f32_16x16x32_bf16(
                    ap[iq], vone, lacc[iq], 0, 0, 0);
            }
            __builtin_amdgcn_s_setprio(0);
        }

        // half 1: keys kbase+32..kbase+63; overwrites Ps
        for (int kk = 0; kk < 2; kk++)
            for (int iq = 0; iq < 2; iq++) {
                bf16x4v pv;
                for (int r = 0; r < 4; r++)
                    pv[r] = (bf16_t)__builtin_amdgcn_exp2f(St[2 + kk][iq][r]);
                *(bf16x4v*)&Ps[w][iq * 16 + l16][kk * 16 + quad * 4] = pv;
            }
        asm volatile("" ::: "memory");

        {   // PV half 1 (+ ones-MFMA row-sum)
            bf16x8 ap[2], bv4[4];
            for (int iq = 0; iq < 2; iq++)
                ap[iq] = *(const bf16x8*)&Ps[w][iq * 16 + l16][quad * 8];
            for (int jn = 0; jn < 4; jn++)
                bv4[jn] = *(const bf16x8*)&Vs[(jn * 16 + l16) * 64 + rc1];
            __builtin_amdgcn_s_setprio(1);
            for (int iq = 0; iq < 2; iq++) {
                for (int jn = 0; jn < 4; jn++)
                    Oacc[iq][jn] = __builtin_amdgcn_mfma_f32_16x16x32_bf16(
                        ap[iq], bv4[jn], Oacc[iq][jn], 0, 0, 0);
                lacc[iq] = __builtin_amdgcn_mfma_f32_16x16x32_bf16(
                    ap[iq], vone, lacc[iq], 0, 0, 0);
            }
            __builtin_amdgcn_s_setprio(0);
        }
    }

    // epilogue: lacc[iq][r] matches Oacc's row layout -> no shuffles.
    for (int iq = 0; iq < 2; iq++) {
        for (int r = 0; r < 4; r++) {
            const float inv = 1.f / lacc[iq][r];
            const int t = qbase + w * 32 + iq * 16 + quad * 4 + r;
            for (int jn = 0; jn < 4; jn++) {
                const int hd = jn * 16 + l16;
                O[(((size_t)(b * T_SEQ + t)) * N_HEADS + h) * HEAD_DIM + hd] =
                    (bf16_t)(Oacc[iq][jn][r] * inv);
            }
        }
    }
}

// ---------------------------------------------------------------------------
extern "C" void kernel_launch(void* const* d_in, const int* in_sizes, int n_in,
                              void* d_out, int out_size, void* d_ws, size_t ws_size,
                              hipStream_t stream)
{
    const float* x  = (const float*)d_in[0];
    const float* wq = (const float*)d_in[1];
    const float* bq = (const float*)d_in[2];
    const float* wk = (const float*)d_in[3];
    const float* bk = (const float*)d_in[4];
    const float* wv = (const float*)d_in[5];
    const float* bv = (const float*)d_in[6];
    const float* wo = (const float*)d_in[7];
    const float* bo = (const float*)d_in[8];
    const float* g  = (const float*)d_in[9];
    const float* be = (const float*)d_in[10];

    char* ws = (char*)d_ws;
    bf16_t* xb   = (bf16_t*)(ws);                        // 8M x 2B        = 16 MB
    bf16_t* wT   = (bf16_t*)(ws + ((size_t)16 << 20));   // 4 x 1M x 2B    =  8 MB
    bf16_t* qkv  = (bf16_t*)(ws + ((size_t)24 << 20));   // 2 x 8M x 2B    = 32 MB (Q,K)
    bf16_t* attn = (bf16_t*)(ws + ((size_t)72 << 20));   // 8M x 2B        = 16 MB
    float*  proj = (float*) (ws + ((size_t)88 << 20));   // 8M x 4B        = 32 MB
    bf16_t* vt   = (bf16_t*)proj;                        // 16 MB, dead before proj written

    // prep: blocks 0..4095 = weight transpose, 4096..6143 = x convert
    prep_k<<<dim3(6144), 256, 0, stream>>>(x, wq, wk, wv, wo, xb, wT);

    // Fused QKV: M=8192 x N=3072, 256x128 tiles -> 768 blocks = 3.0 rounds.
    qkv_k<<<dim3(24, 32), 512, 0, stream>>>(xb, wT, bq, bk, bv, qkv, vt);

    bf16_t* Qm = qkv;
    bf16_t* Km = qkv + (size_t)M_ROWS * D_MODEL;

    attn_k<<<dim3(16, 64), 256, 0, stream>>>(Qm, Km, vt, attn);

    // Fused Proj+LN, cooperative: 256 blocks x 512 thr, 1 block/CU.
    {
        const bf16_t* pa = attn;
        const bf16_t* pb = wT + (size_t)3 * D_MODEL * D_MODEL;
        const float*  pbias = bo;
        float* pproj = proj;
        const float* pg = g;
        const float* pbe = be;
        float* pout = (float*)d_out;
        void* args[] = {(void*)&pa, (void*)&pb, (void*)&pbias, (void*)&pproj,
                        (void*)&pg, (void*)&pbe, (void*)&pout};
        hipLaunchCooperativeKernel((void*)projln_k, dim3(256), dim3(512),
                                   args, 0, stream);
    }
}

// Round 8
// 268.534 us; speedup vs baseline: 1.4756x; 1.4756x over previous
//
#include <hip/hip_runtime.h>
#include <hip/hip_bf16.h>

typedef __bf16 bf16_t;
typedef __bf16 bf16x4v __attribute__((ext_vector_type(4)));
typedef __bf16 bf16x8 __attribute__((ext_vector_type(8)));
typedef float  f32x4  __attribute__((ext_vector_type(4)));

// address-space pointer types for global_load_lds
typedef __attribute__((address_space(1))) void* gptr_t;
typedef __attribute__((address_space(3))) void* lptr_t;

#define B_BATCH  4
#define T_SEQ    2048
#define D_MODEL  1024
#define N_HEADS  16
#define HEAD_DIM 64
#define M_ROWS   (B_BATCH * T_SEQ)   // 8192

#define PROW 40    // attn Ps row elems (80B: 16B-aligned reads, odd-stride banks)

// exp(x/8) = exp2(x * 0.125 * log2(e)); folded into Q at the qkv epilogue
#define EXP2_SCALE 0.1803368801111204f

// ---------------------------------------------------------------------------
// prep_k: fused weight transpose+cast (blocks 0..4095) and x fp32->bf16
// convert (blocks 4096..6143). Independent work, one dispatch instead of two.
// Barrier use is block-uniform. (The ONE new variable vs the 274.6us config.)
// ---------------------------------------------------------------------------
__global__ __launch_bounds__(256) void prep_k(
    const float* __restrict__ x, const float* __restrict__ w0,
    const float* __restrict__ w1, const float* __restrict__ w2,
    const float* __restrict__ w3,
    bf16_t* __restrict__ xb, bf16_t* __restrict__ wT)
{
    __shared__ bf16_t tile[32][33];
    const int bid = blockIdx.x;
    if (bid < 4096) {
        const int z = bid >> 10, rem = bid & 1023;
        const int n0 = (rem & 31) * 32, k0 = (rem >> 5) * 32;
        const float* w = (z == 0) ? w0 : (z == 1) ? w1 : (z == 2) ? w2 : w3;
        bf16_t* o = wT + (size_t)z * D_MODEL * D_MODEL;
        const int tx = threadIdx.x & 31, ty = threadIdx.x >> 5;   // 32 x 8
        for (int i = 0; i < 4; i++)
            tile[ty + i * 8][tx] =
                (bf16_t)w[(size_t)(k0 + ty + i * 8) * D_MODEL + n0 + tx];
        __syncthreads();
        for (int i = 0; i < 4; i++)
            o[(size_t)(n0 + ty + i * 8) * D_MODEL + k0 + tx] = tile[tx][ty + i * 8];
    } else {
        const size_t tid = (size_t)(bid - 4096) * 256 + threadIdx.x;
        for (int rep = 0; rep < 4; rep++) {
            const size_t i = (tid + (size_t)rep * 524288) * 4;
            const f32x4 v = *(const f32x4*)&x[i];
            bf16x4v o;
            for (int e = 0; e < 4; e++) o[e] = (bf16_t)v[e];
            *(bf16x4v*)&xb[i] = o;
        }
    }
}

// ---------------------------------------------------------------------------
// Fused QKV GEMM, 256x128 tile, 8 waves (4M x 2N), BK=64, K-tile dbuf.
// EXACT round-6 version (proven 274.6us config): prefetch issues spread
// across the s-phases (2 A + 1 B per phase). One barrier per K-tile.
// Chunk-XOR swizzle both sides. z==0 (Q) epilogue pre-scales by EXP2_SCALE.
// 768 blocks = exactly 3.0 rounds @ 1 block/CU.
// ---------------------------------------------------------------------------
__global__ __launch_bounds__(512, 2) void qkv_k(
    const bf16_t* __restrict__ A, const bf16_t* __restrict__ BT,
    const float* __restrict__ bq, const float* __restrict__ bk,
    const float* __restrict__ bv,
    bf16_t* __restrict__ qk_out, bf16_t* __restrict__ vt_out)
{
    __shared__ __attribute__((aligned(16))) bf16_t smem[49152];   // 96 KB
    // elems: As[p] at p*16384; Bs[p] at 32768 + p*8192

    const int tid = threadIdx.x;
    const int f0 = blockIdx.y * 24 + blockIdx.x;        // 0..767
    const int f  = (f0 & 7) * 96 + (f0 >> 3);           // bijective XCD swizzle
    const int n_t = f % 24, m_t = f / 24;
    const int m0 = m_t * 256, n0 = n_t * 128;
    const int z  = n0 >> 10;                            // 0=q 1=k 2=v
    const int w = tid >> 6, lane = tid & 63, quad = lane >> 4, l16 = lane & 15;
    const int wm = w >> 1, wn = w & 1;                  // 4M x 2N wave grid
    const int srow = lane >> 3;                         // staging row in 8-group
    const int scol = ((lane & 7) ^ srow) * 8;           // source pre-swizzle
    const int rx = l16 & 7;                             // read-side XOR

    f32x4 acc[4][4] = {};

    // prologue: stage tile 0 into buffer 0 (4 A + 2 B issues per wave)
    for (int it = 0; it < 4; it++) {
        const int R = w * 32 + it * 8;
        __builtin_amdgcn_global_load_lds(
            (gptr_t)&A[(size_t)(m0 + R + srow) * D_MODEL + scol],
            (lptr_t)&smem[R * 64], 16, 0, 0);
    }
    for (int it = 0; it < 2; it++) {
        const int R = w * 16 + it * 8;
        __builtin_amdgcn_global_load_lds(
            (gptr_t)&BT[(size_t)(n0 + R + srow) * D_MODEL + scol],
            (lptr_t)&smem[32768 + R * 64], 16, 0, 0);
    }

    for (int t = 0; t < 16; t++) {
        __syncthreads();   // tile t resident; buf[t^1] free to overwrite
        const bf16_t* Ac = &smem[(t & 1) * 16384];
        const bf16_t* Bc = &smem[32768 + (t & 1) * 8192];
        bf16_t* An = &smem[((t + 1) & 1) * 16384];
        bf16_t* Bn = &smem[32768 + ((t + 1) & 1) * 8192];
        const int kb = (t + 1) * 64;
        const bool pf = (t + 1 < 16);

        #pragma unroll
        for (int s = 0; s < 2; s++) {
            const int rc = ((quad + s * 4) ^ rx) * 8;
            bf16x8 bfr[4];
            #pragma unroll
            for (int j = 0; j < 4; j++)
                bfr[j] = *(const bf16x8*)&Bc[(wn * 64 + j * 16 + l16) * 64 + rc];
            // issue tile t+1 stages: 2 A + 1 B per s-phase
            if (pf) {
                const int RA0 = w * 32 + (s * 2) * 8;
                __builtin_amdgcn_global_load_lds(
                    (gptr_t)&A[(size_t)(m0 + RA0 + srow) * D_MODEL + kb + scol],
                    (lptr_t)&An[RA0 * 64], 16, 0, 0);
                const int RA1 = w * 32 + (s * 2 + 1) * 8;
                __builtin_amdgcn_global_load_lds(
                    (gptr_t)&A[(size_t)(m0 + RA1 + srow) * D_MODEL + kb + scol],
                    (lptr_t)&An[RA1 * 64], 16, 0, 0);
                const int RB = w * 16 + s * 8;
                __builtin_amdgcn_global_load_lds(
                    (gptr_t)&BT[(size_t)(n0 + RB + srow) * D_MODEL + kb + scol],
                    (lptr_t)&Bn[RB * 64], 16, 0, 0);
            }
            bf16x8 af[4];
            #pragma unroll
            for (int i = 0; i < 4; i++)
                af[i] = *(const bf16x8*)&Ac[(wm * 64 + i * 16 + l16) * 64 + rc];
            __builtin_amdgcn_s_setprio(1);
            #pragma unroll
            for (int i = 0; i < 4; i++)
                #pragma unroll
                for (int j = 0; j < 4; j++)
                    acc[i][j] = __builtin_amdgcn_mfma_f32_16x16x32_bf16(
                        af[i], bfr[j], acc[i][j], 0, 0, 0);
            __builtin_amdgcn_s_setprio(0);
        }
    }

    __syncthreads();   // all LDS reads done; alias smem as C-stage

    const float* bias = (z == 0) ? bq : (z == 1) ? bk : bv;
    const float qscale = (z == 0) ? EXP2_SCALE : 1.0f;
    const int ncol0 = n0 & 1023;
    float bj[4];
    for (int j = 0; j < 4; j++)
        bj[j] = bias[ncol0 + wn * 64 + j * 16 + l16];

    const int bidx = m0 >> 11, t0 = m0 & 2047, hbase = ncol0 >> 6;
    if (z < 2) {
        bf16_t (*Cs)[136] = reinterpret_cast<bf16_t(*)[136]>(smem);   // 34816 el
        for (int ai = 0; ai < 4; ai++)
            for (int r = 0; r < 4; r++) {
                const int row = wm * 64 + ai * 16 + quad * 4 + r;
                for (int j = 0; j < 4; j++)
                    Cs[row][wn * 64 + j * 16 + l16] =
                        (bf16_t)((acc[ai][j][r] + bj[j]) * qscale);
            }
        __syncthreads();
        bf16_t* outp = qk_out + (size_t)z * ((size_t)M_ROWS * D_MODEL);
        for (int p = 0; p < 8; p++) {
            const int chunk = p * 512 + tid;
            const int sub = chunk & 15, tt = chunk >> 4;
            const int hl = sub >> 3, sub8 = sub & 7;
            const bf16x8 val = *(const bf16x8*)&Cs[tt][hl * 64 + sub8 * 8];
            *(bf16x8*)&outp[(((size_t)(bidx * N_HEADS + hbase + hl)) * T_SEQ + t0 + tt)
                            * HEAD_DIM + sub8 * 8] = val;
        }
    } else {
        bf16_t (*CsV)[264] = reinterpret_cast<bf16_t(*)[264]>(smem);  // 33792 el
        for (int ai = 0; ai < 4; ai++)
            for (int r = 0; r < 4; r++) {
                const int row = wm * 64 + ai * 16 + quad * 4 + r;
                for (int j = 0; j < 4; j++)
                    CsV[wn * 64 + j * 16 + l16][row] = (bf16_t)(acc[ai][j][r] + bj[j]);
            }
        __syncthreads();
        for (int p = 0; p < 8; p++) {
            const int chunk = p * 512 + tid;
            const int sub = chunk & 31, r = chunk >> 5;
            const int h = hbase + (r >> 6), hd = r & 63;
            const bf16x8 val = *(const bf16x8*)&CsV[r][sub * 8];
            *(bf16x8*)&vt_out[(((size_t)(bidx * N_HEADS + h)) * HEAD_DIM + hd) * T_SEQ
                              + t0 + sub * 8] = val;
        }
    }
}

// ---------------------------------------------------------------------------
// Proj GEMM, 256x128 pipelined template (EXACT round-6 version):
// proj = attn * wo^T + bo. Grid 8 x 32 = 256 blocks = exactly 1.0 round.
// fp32 direct stores. Separate dispatch (cooperative fusion measured at
// +100us grid.sync cost in round 7 — never worth a ~10us boundary).
// ---------------------------------------------------------------------------
__global__ __launch_bounds__(512, 2) void proj_k(
    const bf16_t* __restrict__ A, const bf16_t* __restrict__ BT,
    const float* __restrict__ bias, float* __restrict__ out)
{
    __shared__ __attribute__((aligned(16))) bf16_t smem[49152];   // 96 KB

    const int tid = threadIdx.x;
    const int f0 = blockIdx.y * 8 + blockIdx.x;         // 0..255
    const int f  = (f0 & 7) * 32 + (f0 >> 3);           // bijective XCD swizzle
    const int n_t = f & 7, m_t = f >> 3;
    const int m0 = m_t * 256, n0 = n_t * 128;
    const int w = tid >> 6, lane = tid & 63, quad = lane >> 4, l16 = lane & 15;
    const int wm = w >> 1, wn = w & 1;
    const int srow = lane >> 3;
    const int scol = ((lane & 7) ^ srow) * 8;
    const int rx = l16 & 7;

    f32x4 acc[4][4] = {};

    for (int it = 0; it < 4; it++) {
        const int R = w * 32 + it * 8;
        __builtin_amdgcn_global_load_lds(
            (gptr_t)&A[(size_t)(m0 + R + srow) * D_MODEL + scol],
            (lptr_t)&smem[R * 64], 16, 0, 0);
    }
    for (int it = 0; it < 2; it++) {
        const int R = w * 16 + it * 8;
        __builtin_amdgcn_global_load_lds(
            (gptr_t)&BT[(size_t)(n0 + R + srow) * D_MODEL + scol],
            (lptr_t)&smem[32768 + R * 64], 16, 0, 0);
    }

    for (int t = 0; t < 16; t++) {
        __syncthreads();
        const bf16_t* Ac = &smem[(t & 1) * 16384];
        const bf16_t* Bc = &smem[32768 + (t & 1) * 8192];
        bf16_t* An = &smem[((t + 1) & 1) * 16384];
        bf16_t* Bn = &smem[32768 + ((t + 1) & 1) * 8192];
        const int kb = (t + 1) * 64;
        const bool pf = (t + 1 < 16);

        #pragma unroll
        for (int s = 0; s < 2; s++) {
            const int rc = ((quad + s * 4) ^ rx) * 8;
            bf16x8 bfr[4];
            #pragma unroll
            for (int j = 0; j < 4; j++)
                bfr[j] = *(const bf16x8*)&Bc[(wn * 64 + j * 16 + l16) * 64 + rc];
            if (pf) {
                const int RA0 = w * 32 + (s * 2) * 8;
                __builtin_amdgcn_global_load_lds(
                    (gptr_t)&A[(size_t)(m0 + RA0 + srow) * D_MODEL + kb + scol],
                    (lptr_t)&An[RA0 * 64], 16, 0, 0);
                const int RA1 = w * 32 + (s * 2 + 1) * 8;
                __builtin_amdgcn_global_load_lds(
                    (gptr_t)&A[(size_t)(m0 + RA1 + srow) * D_MODEL + kb + scol],
                    (lptr_t)&An[RA1 * 64], 16, 0, 0);
                const int RB = w * 16 + s * 8;
                __builtin_amdgcn_global_load_lds(
                    (gptr_t)&BT[(size_t)(n0 + RB + srow) * D_MODEL + kb + scol],
                    (lptr_t)&Bn[RB * 64], 16, 0, 0);
            }
            bf16x8 af[4];
            #pragma unroll
            for (int i = 0; i < 4; i++)
                af[i] = *(const bf16x8*)&Ac[(wm * 64 + i * 16 + l16) * 64 + rc];
            __builtin_amdgcn_s_setprio(1);
            #pragma unroll
            for (int i = 0; i < 4; i++)
                #pragma unroll
                for (int j = 0; j < 4; j++)
                    acc[i][j] = __builtin_amdgcn_mfma_f32_16x16x32_bf16(
                        af[i], bfr[j], acc[i][j], 0, 0, 0);
            __builtin_amdgcn_s_setprio(0);
        }
    }

    float bj[4];
    for (int j = 0; j < 4; j++)
        bj[j] = bias[n0 + wn * 64 + j * 16 + l16];

    for (int i = 0; i < 4; i++)
        for (int r = 0; r < 4; r++) {
            const int rg = m0 + wm * 64 + i * 16 + quad * 4 + r;
            for (int j = 0; j < 4; j++) {
                const int cg = n0 + wn * 64 + j * 16 + l16;
                out[(size_t)rg * D_MODEL + cg] = acc[i][j][r] + bj[j];
            }
        }
}

// ---------------------------------------------------------------------------
// Flash attention (unchanged round-6 structure — the 87 us control).
// ---------------------------------------------------------------------------
__global__ __launch_bounds__(256, 4) void attn_k(
    const bf16_t* __restrict__ Q, const bf16_t* __restrict__ K,
    const bf16_t* __restrict__ VT, bf16_t* __restrict__ O)
{
    __shared__ __attribute__((aligned(16))) bf16_t Ks[2][64 * 64];   // 16 KB
    __shared__ __attribute__((aligned(16))) bf16_t Vs[64 * 64];      //  8 KB
    __shared__ __attribute__((aligned(16))) bf16_t Ps[4][32][PROW];  // 10 KB

    const int tid = threadIdx.x;
    const int f = blockIdx.y * 16 + blockIdx.x;
    const int xcd = f & 7, j = f >> 3;
    const int bh = xcd * 8 + (j & 7);
    const int qbase = (j >> 3) * 128;
    const int b = bh >> 4, h = bh & 15;
    const int w = tid >> 6, lane = tid & 63, quad = lane >> 4, l16 = lane & 15;
    const size_t head_off = (size_t)bh * T_SEQ * HEAD_DIM;
    const bf16_t* Qh  = Q  + head_off;
    const bf16_t* Kh  = K  + head_off;
    const bf16_t* VTh = VT + head_off;

    const int srow = lane >> 3;
    const int scol = ((lane & 7) ^ srow) * 8;

    const int rxor = l16 & 7;
    const int rc0 = ((0 + quad) ^ rxor) * 8;
    const int rc1 = ((4 + quad) ^ rxor) * 8;

    bf16x8 bq[2][2];
    for (int iq = 0; iq < 2; iq++)
        for (int s = 0; s < 2; s++)
            bq[iq][s] = *(const bf16x8*)
                &Qh[(size_t)(qbase + w * 32 + iq * 16 + l16) * HEAD_DIM + s * 32 + quad * 8];

    bf16x8 vone;
    for (int e = 0; e < 8; e++) vone[e] = (bf16_t)1.0f;

    for (int it = 0; it < 2; it++) {
        const int R = w * 16 + it * 8;
        __builtin_amdgcn_global_load_lds(
            (gptr_t)&Kh[(size_t)(R + srow) * HEAD_DIM + scol],
            (lptr_t)&Ks[0][R * 64], 16, 0, 0);
    }

    f32x4 Oacc[2][4] = {};
    f32x4 lacc[2] = {};

    for (int kt = 0; kt < T_SEQ / 64; kt++) {
        const int kbase = kt * 64;
        __syncthreads();   // (A) PV(kt-1) reads done; K(kt) resident
        const bf16_t* Kc = Ks[kt & 1];

        for (int it = 0; it < 2; it++) {
            const int R = w * 16 + it * 8;
            __builtin_amdgcn_global_load_lds(
                (gptr_t)&VTh[(size_t)(R + srow) * T_SEQ + kbase + scol],
                (lptr_t)&Vs[R * 64], 16, 0, 0);
        }
        if (kt + 1 < T_SEQ / 64) {
            bf16_t* Kn = Ks[(kt + 1) & 1];
            for (int it = 0; it < 2; it++) {
                const int R = w * 16 + it * 8;
                __builtin_amdgcn_global_load_lds(
                    (gptr_t)&Kh[(size_t)(kbase + 64 + R + srow) * HEAD_DIM + scol],
                    (lptr_t)&Kn[R * 64], 16, 0, 0);
            }
        }

        f32x4 St[4][2] = {};
        for (int s = 0; s < 2; s++) {
            const int rc = s ? rc1 : rc0;
            bf16x8 ak[4];
            for (int jk = 0; jk < 4; jk++)
                ak[jk] = *(const bf16x8*)&Kc[(jk * 16 + l16) * 64 + rc];
            __builtin_amdgcn_s_setprio(1);
            for (int jk = 0; jk < 4; jk++)
                for (int iq = 0; iq < 2; iq++)
                    St[jk][iq] = __builtin_amdgcn_mfma_f32_16x16x32_bf16(
                        ak[jk], bq[iq][s], St[jk][iq], 0, 0, 0);
            __builtin_amdgcn_s_setprio(0);
        }

        // half 0: keys kbase..kbase+31 (Q pre-scaled -> exp2 direct)
        for (int kk = 0; kk < 2; kk++)
            for (int iq = 0; iq < 2; iq++) {
                bf16x4v pv;
                for (int r = 0; r < 4; r++)
                    pv[r] = (bf16_t)__builtin_amdgcn_exp2f(St[kk][iq][r]);
                *(bf16x4v*)&Ps[w][iq * 16 + l16][kk * 16 + quad * 4] = pv;
            }
        asm volatile("" ::: "memory");

        __syncthreads();   // (B) V(kt) + K(kt+1) landed

        {   // PV half 0 (+ ones-MFMA row-sum)
            bf16x8 ap[2], bv4[4];
            for (int iq = 0; iq < 2; iq++)
                ap[iq] = *(const bf16x8*)&Ps[w][iq * 16 + l16][quad * 8];
            for (int jn = 0; jn < 4; jn++)
                bv4[jn] = *(const bf16x8*)&Vs[(jn * 16 + l16) * 64 + rc0];
            __builtin_amdgcn_s_setprio(1);
            for (int iq = 0; iq < 2; iq++) {
                for (int jn = 0; jn < 4; jn++)
                    Oacc[iq][jn] = __builtin_amdgcn_mfma_f32_16x16x32_bf16(
                        ap[iq], bv4[jn], Oacc[iq][jn], 0, 0, 0);
                lacc[iq] = __builtin_amdgcn_mfma_f32_16x16x32_bf16(
                    ap[iq], vone, lacc[iq], 0, 0, 0);
            }
            __builtin_amdgcn_s_setprio(0);
        }

        // half 1: keys kbase+32..kbase+63; overwrites Ps
        for (int kk = 0; kk < 2; kk++)
            for (int iq = 0; iq < 2; iq++) {
                bf16x4v pv;
                for (int r = 0; r < 4; r++)
                    pv[r] = (bf16_t)__builtin_amdgcn_exp2f(St[2 + kk][iq][r]);
                *(bf16x4v*)&Ps[w][iq * 16 + l16][kk * 16 + quad * 4] = pv;
            }
        asm volatile("" ::: "memory");

        {   // PV half 1 (+ ones-MFMA row-sum)
            bf16x8 ap[2], bv4[4];
            for (int iq = 0; iq < 2; iq++)
                ap[iq] = *(const bf16x8*)&Ps[w][iq * 16 + l16][quad * 8];
            for (int jn = 0; jn < 4; jn++)
                bv4[jn] = *(const bf16x8*)&Vs[(jn * 16 + l16) * 64 + rc1];
            __builtin_amdgcn_s_setprio(1);
            for (int iq = 0; iq < 2; iq++) {
                for (int jn = 0; jn < 4; jn++)
                    Oacc[iq][jn] = __builtin_amdgcn_mfma_f32_16x16x32_bf16(
                        ap[iq], bv4[jn], Oacc[iq][jn], 0, 0, 0);
                lacc[iq] = __builtin_amdgcn_mfma_f32_16x16x32_bf16(
                    ap[iq], vone, lacc[iq], 0, 0, 0);
            }
            __builtin_amdgcn_s_setprio(0);
        }
    }

    // epilogue: lacc[iq][r] matches Oacc's row layout -> no shuffles.
    for (int iq = 0; iq < 2; iq++) {
        for (int r = 0; r < 4; r++) {
            const float inv = 1.f / lacc[iq][r];
            const int t = qbase + w * 32 + iq * 16 + quad * 4 + r;
            for (int jn = 0; jn < 4; jn++) {
                const int hd = jn * 16 + l16;
                O[(((size_t)(b * T_SEQ + t)) * N_HEADS + h) * HEAD_DIM + hd] =
                    (bf16_t)(Oacc[iq][jn][r] * inv);
            }
        }
    }
}

// ---------------------------------------------------------------------------
// LayerNorm over last dim (1024): wave-per-row, no LDS, no barrier.
// ---------------------------------------------------------------------------
__global__ __launch_bounds__(256) void ln_k(
    const float* __restrict__ proj, const float* __restrict__ gamma,
    const float* __restrict__ beta, float* __restrict__ out)
{
    const int tid = threadIdx.x;
    const int w = tid >> 6, lane = tid & 63;
    const int row = blockIdx.x * 4 + w;
    const float* p = proj + (size_t)row * D_MODEL;
    f32x4 v[4];
    float s1 = 0.f, s2 = 0.f;
    for (int e = 0; e < 4; e++) {
        v[e] = *(const f32x4*)&p[e * 256 + lane * 4];
        for (int k = 0; k < 4; k++) { s1 += v[e][k]; s2 += v[e][k] * v[e][k]; }
    }
    for (int off = 32; off >= 1; off >>= 1) {
        s1 += __shfl_xor(s1, off, 64);
        s2 += __shfl_xor(s2, off, 64);
    }
    const float mu  = s1 * (1.f / D_MODEL);
    const float var = s2 * (1.f / D_MODEL) - mu * mu;
    const float rstd = rsqrtf(var + 1e-5f);
    float* o = out + (size_t)row * D_MODEL;
    for (int e = 0; e < 4; e++) {
        const int c = e * 256 + lane * 4;
        const f32x4 g4 = *(const f32x4*)&gamma[c];
        const f32x4 b4 = *(const f32x4*)&beta[c];
        f32x4 ov;
        for (int k = 0; k < 4; k++) ov[k] = (v[e][k] - mu) * rstd * g4[k] + b4[k];
        *(f32x4*)&o[c] = ov;
    }
}

// ---------------------------------------------------------------------------
extern "C" void kernel_launch(void* const* d_in, const int* in_sizes, int n_in,
                              void* d_out, int out_size, void* d_ws, size_t ws_size,
                              hipStream_t stream)
{
    const float* x  = (const float*)d_in[0];
    const float* wq = (const float*)d_in[1];
    const float* bq = (const float*)d_in[2];
    const float* wk = (const float*)d_in[3];
    const float* bk = (const float*)d_in[4];
    const float* wv = (const float*)d_in[5];
    const float* bv = (const float*)d_in[6];
    const float* wo = (const float*)d_in[7];
    const float* bo = (const float*)d_in[8];
    const float* g  = (const float*)d_in[9];
    const float* be = (const float*)d_in[10];

    char* ws = (char*)d_ws;
    bf16_t* xb   = (bf16_t*)(ws);                        // 8M x 2B        = 16 MB
    bf16_t* wT   = (bf16_t*)(ws + ((size_t)16 << 20));   // 4 x 1M x 2B    =  8 MB
    bf16_t* qkv  = (bf16_t*)(ws + ((size_t)24 << 20));   // 2 x 8M x 2B    = 32 MB (Q,K)
    bf16_t* attn = (bf16_t*)(ws + ((size_t)72 << 20));   // 8M x 2B        = 16 MB
    float*  proj = (float*) (ws + ((size_t)88 << 20));   // 8M x 4B        = 32 MB
    bf16_t* vt   = (bf16_t*)proj;                        // 16 MB, dead before proj written

    // prep: blocks 0..4095 = weight transpose, 4096..6143 = x convert
    prep_k<<<dim3(6144), 256, 0, stream>>>(x, wq, wk, wv, wo, xb, wT);

    // Fused QKV: M=8192 x N=3072, 256x128 tiles -> 768 blocks = 3.0 rounds.
    qkv_k<<<dim3(24, 32), 512, 0, stream>>>(xb, wT, bq, bk, bv, qkv, vt);

    bf16_t* Qm = qkv;
    bf16_t* Km = qkv + (size_t)M_ROWS * D_MODEL;

    attn_k<<<dim3(16, 64), 256, 0, stream>>>(Qm, Km, vt, attn);

    // Proj: M=8192 x N=1024, 256x128 tiles -> 256 blocks = 1.0 round.
    proj_k<<<dim3(8, 32), 512, 0, stream>>>(
        attn, wT + (size_t)3 * D_MODEL * D_MODEL, bo, (float*)proj);

    ln_k<<<dim3(M_ROWS / 4), 256, 0, stream>>>(proj, g, be, (float*)d_out);
}